// Round 2
// baseline (464.087 us; speedup 1.0000x reference)
//
#include <hip/hip_runtime.h>

// Problem constants: B=4, K=16, H=480, W=640, P=200000, C=3
constexpr int B_ = 4, K_ = 16, H_ = 480, W_ = 640, P_ = 200000;
constexpr int HW   = H_ * W_;     // 307200 pixels per (b,k) plane
constexpr int PIX4 = HW / 4;      // 76800 float4-groups per plane

// Pre-pass: ptclds (3,P) -> (P,4) padded float4 so the main kernel gathers
// one 16B line segment per (pixel,k) instead of 3 scattered dwords.
__global__ __launch_bounds__(256) void transpose_pts(
    const float* __restrict__ ptclds, float4* __restrict__ pts4)
{
    const int i = blockIdx.x * 256 + threadIdx.x;
    if (i < P_) {
        pts4[i] = make_float4(ptclds[i], ptclds[P_ + i], ptclds[2 * P_ + i], 0.f);
    }
}

__global__ __launch_bounds__(256, 4) void compositor_kernel(
    const int*    __restrict__ frag,    // (B,K,H,W) int32
    const float*  __restrict__ alpha,   // (B,K,H,W) f32
    const float4* __restrict__ pts4,    // (P,4) f32 transposed point cloud
    const float*  __restrict__ im,      // (C,H,W) f32
    float*        __restrict__ out)     // (B,C,H,W) f32
{
    const int t = blockIdx.x * blockDim.x + threadIdx.x;   // [0, B_*PIX4)
    const int b = t / PIX4;
    const int g = t - b * PIX4;
    const int p = g * 4;

    const int4*   fb = (const int4*)  (frag  + (size_t)b * K_ * HW + p);
    const float4* ab = (const float4*)(alpha + (size_t)b * K_ * HW + p);

    float T[4]      = {1.f, 1.f, 1.f, 1.f};
    float acc[3][4] = {{0.f,0.f,0.f,0.f},{0.f,0.f,0.f,0.f},{0.f,0.f,0.f,0.f}};

    int f0[4];
    {
        int4 v = fb[0];
        f0[0] = v.x; f0[1] = v.y; f0[2] = v.z; f0[3] = v.w;
    }

    #pragma unroll
    for (int k = 0; k < K_; ++k) {
        int4   fv = fb[(size_t)k * PIX4];
        float4 av = ab[(size_t)k * PIX4];
        int   fi[4] = {fv.x, fv.y, fv.z, fv.w};
        float ai[4] = {av.x, av.y, av.z, av.w};

        #pragma unroll
        for (int j = 0; j < 4; ++j) {
            const bool valid = fi[j] >= 0;
            const float a = valid ? ai[j] : 0.0f;
            const float w = a * T[j];          // a * exclusive cumprod(1-a)
            T[j] *= (1.0f - a);
            const int idx = valid ? fi[j] : 0; // clip(frag, 0)
            float4 pt = pts4[idx];             // single 16B gather, all 3 channels
            acc[0][j] += w * pt.x;
            acc[1][j] += w * pt.y;
            acc[2][j] += w * pt.z;
        }
    }

    #pragma unroll
    for (int c = 0; c < 3; ++c) {
        float o[4];
        #pragma unroll
        for (int j = 0; j < 4; ++j) {
            o[j] = (f0[j] < 0) ? im[(size_t)c * HW + p + j] : acc[c][j];
        }
        *(float4*)(out + ((size_t)b * 3 + c) * HW + p) =
            make_float4(o[0], o[1], o[2], o[3]);
    }
}

// Fallback (no workspace): original 3-gather kernel, known-correct.
__global__ __launch_bounds__(256) void compositor_kernel_direct(
    const int*   __restrict__ frag,
    const float* __restrict__ alpha,
    const float* __restrict__ ptclds,
    const float* __restrict__ im,
    float*       __restrict__ out)
{
    const int t = blockIdx.x * blockDim.x + threadIdx.x;
    const int b = t / PIX4;
    const int g = t - b * PIX4;
    const int p = g * 4;

    const int4*   fb = (const int4*)  (frag  + (size_t)b * K_ * HW + p);
    const float4* ab = (const float4*)(alpha + (size_t)b * K_ * HW + p);

    float T[4]      = {1.f, 1.f, 1.f, 1.f};
    float acc[3][4] = {{0.f,0.f,0.f,0.f},{0.f,0.f,0.f,0.f},{0.f,0.f,0.f,0.f}};

    int f0[4];
    {
        int4 v = fb[0];
        f0[0] = v.x; f0[1] = v.y; f0[2] = v.z; f0[3] = v.w;
    }

    #pragma unroll
    for (int k = 0; k < K_; ++k) {
        int4   fv = fb[(size_t)k * PIX4];
        float4 av = ab[(size_t)k * PIX4];
        int   fi[4] = {fv.x, fv.y, fv.z, fv.w};
        float ai[4] = {av.x, av.y, av.z, av.w};

        #pragma unroll
        for (int j = 0; j < 4; ++j) {
            const bool valid = fi[j] >= 0;
            const float a = valid ? ai[j] : 0.0f;
            const float w = a * T[j];
            T[j] *= (1.0f - a);
            const int idx = valid ? fi[j] : 0;
            acc[0][j] += w * ptclds[idx];
            acc[1][j] += w * ptclds[P_   + idx];
            acc[2][j] += w * ptclds[2*P_ + idx];
        }
    }

    #pragma unroll
    for (int c = 0; c < 3; ++c) {
        float o[4];
        #pragma unroll
        for (int j = 0; j < 4; ++j) {
            o[j] = (f0[j] < 0) ? im[(size_t)c * HW + p + j] : acc[c][j];
        }
        *(float4*)(out + ((size_t)b * 3 + c) * HW + p) =
            make_float4(o[0], o[1], o[2], o[3]);
    }
}

extern "C" void kernel_launch(void* const* d_in, const int* in_sizes, int n_in,
                              void* d_out, int out_size, void* d_ws, size_t ws_size,
                              hipStream_t stream) {
    const int*   frag   = (const int*)  d_in[0];
    const float* alpha  = (const float*)d_in[1];
    const float* ptclds = (const float*)d_in[2];
    const float* im     = (const float*)d_in[3];
    float*       out    = (float*)d_out;

    const int total_threads = B_ * PIX4;   // 307200
    const size_t need = (size_t)P_ * sizeof(float4);  // 3.2 MB

    if (ws_size >= need) {
        float4* pts4 = (float4*)d_ws;
        transpose_pts<<<(P_ + 255) / 256, 256, 0, stream>>>(ptclds, pts4);
        compositor_kernel<<<total_threads / 256, 256, 0, stream>>>(
            frag, alpha, pts4, im, out);
    } else {
        compositor_kernel_direct<<<total_threads / 256, 256, 0, stream>>>(
            frag, alpha, ptclds, im, out);
    }
}

// Round 3
// 319.596 us; speedup vs baseline: 1.4521x; 1.4521x over previous
//
#include <hip/hip_runtime.h>

// Problem constants: B=4, K=16, H=480, W=640, P=200000, C=3
constexpr int B_ = 4, K_ = 16, H_ = 480, W_ = 640, P_ = 200000;
constexpr int HW = H_ * W_;   // 307200 pixels per (b,k) plane

// One thread per pixel. Stage ALL loads into register arrays first (16 frag,
// 16 alpha, 48 gathers all in flight -> ~80 outstanding loads/thread of MLP),
// then run the cheap serial transmittance math on registers.
// Keep ptclds in its native (3,P) layout: 2.4 MB, 4B entries -> L2-resident.
// (R2 post-mortem: a (P,4) float4 table thrashed L2 via 128B sectors/gather.)
__global__ __launch_bounds__(256, 4) void compositor_kernel(
    const int*   __restrict__ frag,    // (B,K,H,W) int32
    const float* __restrict__ alpha,   // (B,K,H,W) f32
    const float* __restrict__ ptclds,  // (3,P) f32
    const float* __restrict__ im,      // (3,H,W) f32
    float*       __restrict__ out)     // (B,3,H,W) f32
{
    const int t = blockIdx.x * blockDim.x + threadIdx.x;   // [0, B_*HW)
    const int b = t / HW;
    const int p = t - b * HW;

    const int*   fb = frag  + (size_t)b * K_ * HW + p;
    const float* ab = alpha + (size_t)b * K_ * HW + p;

    // 1) all fragment indices (gather addresses depend on these)
    int fi[K_];
    #pragma unroll
    for (int k = 0; k < K_; ++k) fi[k] = fb[(size_t)k * HW];

    // 2) all alphas (independent stream, issues alongside)
    float ai[K_];
    #pragma unroll
    for (int k = 0; k < K_; ++k) ai[k] = ab[(size_t)k * HW];

    // 3) all 48 gathers in flight at once
    float pr[K_], pg[K_], pb[K_];
    #pragma unroll
    for (int k = 0; k < K_; ++k) {
        const int idx = fi[k] >= 0 ? fi[k] : 0;   // clip(frag, 0)
        pr[k] = ptclds[idx];
        pg[k] = ptclds[P_   + idx];
        pb[k] = ptclds[2*P_ + idx];
    }

    // 4) serial compositing math, registers only
    float T = 1.f, a0 = 0.f, a1 = 0.f, a2 = 0.f;
    #pragma unroll
    for (int k = 0; k < K_; ++k) {
        const float a = fi[k] >= 0 ? ai[k] : 0.0f;
        const float w = a * T;        // a * exclusive cumprod(1-a)
        T *= (1.0f - a);
        a0 += w * pr[k];
        a1 += w * pg[k];
        a2 += w * pb[k];
    }

    // 5) background override + store (lane-consecutive dwords, coalesced)
    const bool bg = fi[0] < 0;
    out[((size_t)b * 3 + 0) * HW + p] = bg ? im[p]          : a0;
    out[((size_t)b * 3 + 1) * HW + p] = bg ? im[HW + p]     : a1;
    out[((size_t)b * 3 + 2) * HW + p] = bg ? im[2 * HW + p] : a2;
}

extern "C" void kernel_launch(void* const* d_in, const int* in_sizes, int n_in,
                              void* d_out, int out_size, void* d_ws, size_t ws_size,
                              hipStream_t stream) {
    const int*   frag   = (const int*)  d_in[0];
    const float* alpha  = (const float*)d_in[1];
    const float* ptclds = (const float*)d_in[2];
    const float* im     = (const float*)d_in[3];
    float*       out    = (float*)d_out;

    const int total_threads = B_ * HW;   // 1,228,800
    compositor_kernel<<<total_threads / 256, 256, 0, stream>>>(
        frag, alpha, ptclds, im, out);
}

// Round 4
// 227.861 us; speedup vs baseline: 2.0367x; 1.4026x over previous
//
#include <hip/hip_runtime.h>

// Problem constants: B=4, K=16, H=480, W=640, P=200000, C=3
constexpr int B_ = 4, K_ = 16, H_ = 480, W_ = 640, P_ = 200000;
constexpr int HW = H_ * W_;   // 307200 pixels per (b,k) plane

// Pre-pass: ptclds (3,P) -> (P,4) float4 table (3.2 MB). One 16B gather per
// (pixel,k) instead of three 4B gathers -> 3x fewer scattered wave-instrs.
__global__ __launch_bounds__(256) void transpose_pts(
    const float* __restrict__ ptclds, float4* __restrict__ pts4)
{
    const int i = blockIdx.x * 256 + threadIdx.x;
    if (i < P_) {
        pts4[i] = make_float4(ptclds[i], ptclds[P_ + i], ptclds[2 * P_ + i], 0.f);
    }
}

// One thread per pixel; all loads staged into register arrays for max MLP.
// R2 post-mortem: the float4 table thrashed L2 (FETCH 600 MB) because the
// 157 MB frag/alpha stream evicted it. Fix: mark ALL streaming traffic
// non-temporal (evict-first) so the 3.2 MB table stays L2-resident.
__global__ __launch_bounds__(256, 4) void compositor_kernel(
    const int*    __restrict__ frag,    // (B,K,H,W) int32
    const float*  __restrict__ alpha,   // (B,K,H,W) f32
    const float4* __restrict__ pts4,    // (P,4) f32 table
    const float*  __restrict__ im,      // (3,H,W) f32
    float*        __restrict__ out)     // (B,3,H,W) f32
{
    const int t = blockIdx.x * blockDim.x + threadIdx.x;   // [0, B_*HW)
    const int b = t / HW;
    const int p = t - b * HW;

    const int*   fb = frag  + (size_t)b * K_ * HW + p;
    const float* ab = alpha + (size_t)b * K_ * HW + p;

    // 1) fragment indices (streaming, non-temporal)
    int fi[K_];
    #pragma unroll
    for (int k = 0; k < K_; ++k) fi[k] = __builtin_nontemporal_load(fb + (size_t)k * HW);

    // 2) alphas (streaming, non-temporal)
    float ai[K_];
    #pragma unroll
    for (int k = 0; k < K_; ++k) ai[k] = __builtin_nontemporal_load(ab + (size_t)k * HW);

    // 3) all 16 table gathers in flight (normal loads -> cache in L2)
    float4 pt[K_];
    #pragma unroll
    for (int k = 0; k < K_; ++k) {
        const int idx = fi[k] >= 0 ? fi[k] : 0;   // clip(frag, 0)
        pt[k] = pts4[idx];
    }

    // 4) serial compositing math, registers only
    float T = 1.f, a0 = 0.f, a1 = 0.f, a2 = 0.f;
    #pragma unroll
    for (int k = 0; k < K_; ++k) {
        const float a = fi[k] >= 0 ? ai[k] : 0.0f;
        const float w = a * T;        // a * exclusive cumprod(1-a)
        T *= (1.0f - a);
        a0 += w * pt[k].x;
        a1 += w * pt[k].y;
        a2 += w * pt[k].z;
    }

    // 5) background override + non-temporal coalesced stores
    const bool bg = fi[0] < 0;
    const float o0 = bg ? im[p]          : a0;
    const float o1 = bg ? im[HW + p]     : a1;
    const float o2 = bg ? im[2 * HW + p] : a2;
    __builtin_nontemporal_store(o0, out + ((size_t)b * 3 + 0) * HW + p);
    __builtin_nontemporal_store(o1, out + ((size_t)b * 3 + 1) * HW + p);
    __builtin_nontemporal_store(o2, out + ((size_t)b * 3 + 2) * HW + p);
}

extern "C" void kernel_launch(void* const* d_in, const int* in_sizes, int n_in,
                              void* d_out, int out_size, void* d_ws, size_t ws_size,
                              hipStream_t stream) {
    const int*   frag   = (const int*)  d_in[0];
    const float* alpha  = (const float*)d_in[1];
    const float* ptclds = (const float*)d_in[2];
    const float* im     = (const float*)d_in[3];
    float*       out    = (float*)d_out;

    float4* pts4 = (float4*)d_ws;  // 3.2 MB < ws_size
    transpose_pts<<<(P_ + 255) / 256, 256, 0, stream>>>(ptclds, pts4);

    const int total_threads = B_ * HW;   // 1,228,800
    compositor_kernel<<<total_threads / 256, 256, 0, stream>>>(
        frag, alpha, pts4, im, out);
}